// Round 9
// baseline (555.299 us; speedup 1.0000x reference)
//
#include <hip/hip_runtime.h>

typedef unsigned short u16;
typedef unsigned int u32;
typedef __bf16 bf16x8 __attribute__((ext_vector_type(8)));
typedef float floatx4 __attribute__((ext_vector_type(4)));

#define HID 1024
#define BATCH 64
#define SEQ 256
#define INDIM 128
#define OUTDIM 128
#define MROWS (BATCH*SEQ)   // 16384

__device__ __forceinline__ float b2f(u16 u) {
    union { u32 u; float f; } v; v.u = ((u32)u) << 16; return v.f;
}
__device__ __forceinline__ u16 f2b(float f) {
    union { float f; u32 u; } v; v.f = f;
    u32 x = v.u;
    x += 0x7fffu + ((x >> 16) & 1u);
    return (u16)(x >> 16);
}
__device__ __forceinline__ float sigm(float x) { return 1.f / (1.f + __expf(-x)); }
__device__ __forceinline__ float tanh_f(float x) { return 2.f / (1.f + __expf(-2.f * x)) - 1.f; }

__device__ __forceinline__ void gld16(const u16* g, u16* l) {
    __builtin_amdgcn_global_load_lds(
        (const __attribute__((address_space(1))) void*)g,
        (__attribute__((address_space(3))) void*)l, 16, 0, 0);
}

// ---------------------------------------------------------------------------
// inline dtype detect: probe is l0_Wh (uniform ±1/32). bf16 -> exp field
// <= 121 always. fp32 misread -> ~50%/sample exp>=127; 64 samples -> certain.
// ---------------------------------------------------------------------------
__device__ __forceinline__ int is_fp32(const u16* probe) {
    const int lane = threadIdx.x & 63;
    const int e = (probe[lane * 7] >> 7) & 0xff;
    return __ballot(e >= 127) != 0ULL;
}

// ---------------------------------------------------------------------------
// ONE prep dispatch: z 0..9 transpose weights [R,C]->[C,R] (+elem offset for
// depth-1 slices); z 10..16 convert x + 6 bias vectors. Dtype self-detected.
// ---------------------------------------------------------------------------
struct PrepList {
    const void* s[17];
    u16*        d[17];
    int         R[17];      // transpose: rows; convert: elem count
    int         Cc[17];
    long        off[17];
    const u16*  probe;
};

__global__ void prep_all(PrepList L) {
    const int fp32 = is_fp32(L.probe);
    const int z = blockIdx.z;
    const void* src = L.s[z];
    u16*        dst = L.d[z];
    if (z >= 10) {   // convert, grid-stride over n
        const int n = L.R[z];
        const int tid = threadIdx.y * 32 + threadIdx.x;
        const int blk = blockIdx.y * 32 + blockIdx.x;
        const int stride = 1024 * 256;
        for (int i = blk * 256 + tid; i < n; i += stride) {
            u16 o;
            if (fp32) o = f2b(((const float*)src)[i]);
            else      o = ((const u16*)src)[i];
            dst[i] = o;
        }
        return;
    }
    const int R  = L.R[z];
    const int Cc = L.Cc[z];
    const long zo = L.off[z];
    const int tr = blockIdx.y * 32, tc = blockIdx.x * 32;
    if (tr >= R || tc >= Cc) return;           // block-uniform
    __align__(16) __shared__ u16 t[32][33];
    const int tx = threadIdx.x, ty = threadIdx.y;   // (32,8)
#pragma unroll
    for (int i = 0; i < 4; ++i) {
        const int r = ty + i * 8;
        const long e = zo + (long)(tr + r) * Cc + tc + tx;
        u16 v;
        if (fp32) v = f2b(((const float*)src)[e]);
        else      v = ((const u16*)src)[e];
        t[r][tx] = v;
    }
    __syncthreads();
#pragma unroll
    for (int i = 0; i < 4; ++i) {
        const int r = ty + i * 8;
        dst[(size_t)(tc + r) * R + tr + tx] = t[tx][r];
    }
}

// ---------------------------------------------------------------------------
// XCD-aware block remap (1024-block BN=128 grids)
// ---------------------------------------------------------------------------
__device__ __forceinline__ void tile_swizzle(int& m0, int& n0) {
    const int lin = blockIdx.y * gridDim.x + blockIdx.x;  // 0..1023
    const int xcd = lin & 7;
    const int loc = lin >> 3;
    m0 = (xcd * 16 + (loc & 15)) * 128;
    n0 = (loc >> 4) * 128;
}

// ---------------------------------------------------------------------------
// 128x128-tile bf16 MFMA GEMM, BK=64, XOR-swizzled global_load_lds staging,
// bias epilogue. Used only for the K=128 Win0 GEMM (2 K-iters).
// ---------------------------------------------------------------------------
__global__ __launch_bounds__(256, 2) void gemm128(
    const u16* __restrict__ A, const u16* __restrict__ BT,
    const u16* __restrict__ bias, u16* __restrict__ C,
    int M, int N, int K)
{
    __align__(16) __shared__ u16 As[128 * 64];
    __align__(16) __shared__ u16 Bs[128 * 64];

    const int tid  = threadIdx.x;
    const int lane = tid & 63;
    const int wid  = tid >> 6;
    const int wr   = wid >> 1;
    const int wc   = wid & 1;

    int m0, n0;
    tile_swizzle(m0, n0);

    floatx4 acc[4][4] = {};

    const int srow = lane >> 3;
    const int scol = 8 * ((lane & 7) ^ (lane >> 3));
    const int cb   = wid * 4;
    const u16* Ag[4]; const u16* Bg[4];
    u16 *Al[4], *Bl[4];
#pragma unroll
    for (int j = 0; j < 4; ++j) {
        const int c = cb + j;
        const int r = c * 8 + srow;
        Ag[j] = A  + (size_t)(m0 + r) * K + scol;
        Bg[j] = BT + (size_t)(n0 + r) * K + scol;
        Al[j] = As + c * 512;
        Bl[j] = Bs + c * 512;
    }

    const int quad = lane >> 4;
    const int l16  = lane & 15;
    const int swz  = l16 & 7;

    const int nk = K >> 6;
    for (int kt = 0; kt < nk; ++kt) {
        __syncthreads();
#pragma unroll
        for (int j = 0; j < 4; ++j) {
            gld16(Ag[j], Al[j]);  gld16(Bg[j], Bl[j]);
            Ag[j] += 64; Bg[j] += 64;
        }
        __syncthreads();

#pragma unroll
        for (int kk = 0; kk < 2; ++kk) {
            const int slot = ((kk * 4 + quad) ^ swz) * 8;
            bf16x8 af[4], bfr[4];
#pragma unroll
            for (int i = 0; i < 4; ++i) {
                af[i]  = *(const bf16x8*)(As + (wr * 64 + i * 16 + l16) * 64 + slot);
                bfr[i] = *(const bf16x8*)(Bs + (wc * 64 + i * 16 + l16) * 64 + slot);
            }
#pragma unroll
            for (int i = 0; i < 4; ++i)
#pragma unroll
                for (int j = 0; j < 4; ++j)
                    acc[i][j] = __builtin_amdgcn_mfma_f32_16x16x32_bf16(af[i], bfr[j], acc[i][j], 0, 0, 0);
        }
    }

#pragma unroll
    for (int i = 0; i < 4; ++i) {
        const int rowb = m0 + wr * 64 + i * 16 + quad * 4;
#pragma unroll
        for (int j = 0; j < 4; ++j) {
            const int col = n0 + wc * 64 + j * 16 + l16;
            const float bv = b2f(bias[col]);
#pragma unroll
            for (int r = 0; r < 4; ++r)
                C[(size_t)(rowb + r) * N + col] = f2b(acc[i][j][r] + bv);
        }
    }
}

// ---------------------------------------------------------------------------
// High-occupancy single-gate GEMM: BM=128, BN=64, BK=64, 2x2 wave grid,
// wave-tile 64x32 (balanced A/B LDS traffic), 32 acc regs -> 4 blocks/CU.
// ---------------------------------------------------------------------------
__global__ __launch_bounds__(256, 4) void gemm64n(
    const u16* __restrict__ A, const u16* __restrict__ BT,
    const u16* __restrict__ bias, u16* __restrict__ C,
    int M, int N, int K)
{
    __align__(16) __shared__ u16 As[128 * 64];
    __align__(16) __shared__ u16 Bs[64 * 64];

    const int tid  = threadIdx.x;
    const int lane = tid & 63;
    const int wid  = tid >> 6;
    const int wr   = wid >> 1;   // m half (64 rows)
    const int wc   = wid & 1;    // n half (32 cols)

    const int lin = blockIdx.y * gridDim.x + blockIdx.x;  // 0..2047
    const int xcd = lin & 7;
    const int loc = lin >> 3;
    const int m0 = (xcd * 16 + (loc & 15)) * 128;
    const int n0 = (loc >> 4) * 64;

    floatx4 acc[4][2] = {};

    const int srow = lane >> 3;
    const int scol = 8 * ((lane & 7) ^ (lane >> 3));
    const u16* Ag[4]; const u16* Bg[2];
    u16 *Al[4], *Bl[2];
#pragma unroll
    for (int j = 0; j < 4; ++j) {
        const int c = wid * 4 + j;
        Ag[j] = A + (size_t)(m0 + c * 8 + srow) * K + scol;
        Al[j] = As + c * 512;
    }
#pragma unroll
    for (int j = 0; j < 2; ++j) {
        const int c = wid * 2 + j;
        Bg[j] = BT + (size_t)(n0 + c * 8 + srow) * K + scol;
        Bl[j] = Bs + c * 512;
    }

    const int quad = lane >> 4;
    const int l16  = lane & 15;
    const int swz  = l16 & 7;

    const int nk = K >> 6;
    for (int kt = 0; kt < nk; ++kt) {
        __syncthreads();
#pragma unroll
        for (int j = 0; j < 4; ++j) { gld16(Ag[j], Al[j]); Ag[j] += 64; }
#pragma unroll
        for (int j = 0; j < 2; ++j) { gld16(Bg[j], Bl[j]); Bg[j] += 64; }
        __syncthreads();

#pragma unroll
        for (int kk = 0; kk < 2; ++kk) {
            const int slot = ((kk * 4 + quad) ^ swz) * 8;
            bf16x8 af[4], bf[2];
#pragma unroll
            for (int i = 0; i < 4; ++i)
                af[i] = *(const bf16x8*)(As + (wr * 64 + i * 16 + l16) * 64 + slot);
#pragma unroll
            for (int j = 0; j < 2; ++j)
                bf[j] = *(const bf16x8*)(Bs + (wc * 32 + j * 16 + l16) * 64 + slot);
#pragma unroll
            for (int i = 0; i < 4; ++i)
#pragma unroll
                for (int j = 0; j < 2; ++j)
                    acc[i][j] = __builtin_amdgcn_mfma_f32_16x16x32_bf16(af[i], bf[j], acc[i][j], 0, 0, 0);
        }
    }

#pragma unroll
    for (int i = 0; i < 4; ++i) {
        const int rowb = m0 + wr * 64 + i * 16 + quad * 4;
#pragma unroll
        for (int j = 0; j < 2; ++j) {
            const int col = n0 + wc * 32 + j * 16 + l16;
            const float bv = b2f(bias[col]);
#pragma unroll
            for (int r = 0; r < 4; ++r)
                C[(size_t)(rowb + r) * N + col] = f2b(acc[i][j][r] + bv);
        }
    }
}

// ---------------------------------------------------------------------------
// Fused highway GEMM: BM=128, BN=64, BK=64, 2x2 wave grid, wave-tile 64x32
// (balanced A/B LDS traffic: 64 KB/block-iter vs 80 at 32x64), dual acc
// (4x2 frags x 2 gates = 64 regs), 3 blocks/CU.
// h_new = h_old + sig(t)*(tanh(h)-h_old), h_old re-read from A.
// ---------------------------------------------------------------------------
__global__ __launch_bounds__(256, 3) void gemm_hw(
    const u16* __restrict__ A,      // [M,K] = h
    const u16* __restrict__ WtT,    // [N,K]
    const u16* __restrict__ WhT,    // [N,K]
    const u16* __restrict__ bt, const u16* __restrict__ bh,
    u16* __restrict__ Hout,
    int M, int N, int K)
{
    __align__(16) __shared__ u16 As [128 * 64];
    __align__(16) __shared__ u16 Bts[64 * 64];
    __align__(16) __shared__ u16 Bhs[64 * 64];

    const int tid  = threadIdx.x;
    const int lane = tid & 63;
    const int wid  = tid >> 6;
    const int wr   = wid >> 1;   // m half (64 rows)
    const int wc   = wid & 1;    // n half (32 cols)

    const int lin = blockIdx.y * gridDim.x + blockIdx.x;  // 0..2047
    const int xcd = lin & 7;
    const int loc = lin >> 3;
    const int m0 = (xcd * 16 + (loc & 15)) * 128;
    const int n0 = (loc >> 4) * 64;

    floatx4 acct[4][2] = {};
    floatx4 acch[4][2] = {};

    const int srow = lane >> 3;
    const int scol = 8 * ((lane & 7) ^ (lane >> 3));
    const u16* Ag[4]; const u16* Tg[2]; const u16* Hg[2];
    u16 *Al[4], *Tl[2], *Hl[2];
#pragma unroll
    for (int j = 0; j < 4; ++j) {
        const int c = wid * 4 + j;
        Ag[j] = A + (size_t)(m0 + c * 8 + srow) * K + scol;
        Al[j] = As + c * 512;
    }
#pragma unroll
    for (int j = 0; j < 2; ++j) {
        const int c = wid * 2 + j;
        Tg[j] = WtT + (size_t)(n0 + c * 8 + srow) * K + scol;
        Hg[j] = WhT + (size_t)(n0 + c * 8 + srow) * K + scol;
        Tl[j] = Bts + c * 512;
        Hl[j] = Bhs + c * 512;
    }

    const int quad = lane >> 4;
    const int l16  = lane & 15;
    const int swz  = l16 & 7;

    const int nk = K >> 6;
    for (int kt = 0; kt < nk; ++kt) {
        __syncthreads();
#pragma unroll
        for (int j = 0; j < 4; ++j) { gld16(Ag[j], Al[j]); Ag[j] += 64; }
#pragma unroll
        for (int j = 0; j < 2; ++j) {
            gld16(Tg[j], Tl[j]); Tg[j] += 64;
            gld16(Hg[j], Hl[j]); Hg[j] += 64;
        }
        __syncthreads();

#pragma unroll
        for (int kk = 0; kk < 2; ++kk) {
            const int slot = ((kk * 4 + quad) ^ swz) * 8;
            bf16x8 af[4], btf[2], bhf[2];
#pragma unroll
            for (int i = 0; i < 4; ++i)
                af[i] = *(const bf16x8*)(As + (wr * 64 + i * 16 + l16) * 64 + slot);
#pragma unroll
            for (int j = 0; j < 2; ++j) {
                btf[j] = *(const bf16x8*)(Bts + (wc * 32 + j * 16 + l16) * 64 + slot);
                bhf[j] = *(const bf16x8*)(Bhs + (wc * 32 + j * 16 + l16) * 64 + slot);
            }
#pragma unroll
            for (int i = 0; i < 4; ++i)
#pragma unroll
                for (int j = 0; j < 2; ++j) {
                    acct[i][j] = __builtin_amdgcn_mfma_f32_16x16x32_bf16(af[i], btf[j], acct[i][j], 0, 0, 0);
                    acch[i][j] = __builtin_amdgcn_mfma_f32_16x16x32_bf16(af[i], bhf[j], acch[i][j], 0, 0, 0);
                }
        }
    }

#pragma unroll
    for (int i = 0; i < 4; ++i) {
        const int rowb = m0 + wr * 64 + i * 16 + quad * 4;
#pragma unroll
        for (int j = 0; j < 2; ++j) {
            const int col = n0 + wc * 32 + j * 16 + l16;
            const float btv = b2f(bt[col]);
            const float bhv = b2f(bh[col]);
#pragma unroll
            for (int r = 0; r < 4; ++r) {
                const size_t idx = (size_t)(rowb + r) * N + col;
                const float hold = b2f(A[idx]);
                const float tg = sigm(acct[i][j][r] + btv);
                const float hl = tanh_f(acch[i][j][r] + bhv);
                Hout[idx] = f2b(hold + tg * (hl - hold));
            }
        }
    }
}

// ---------------------------------------------------------------------------
// two-pass parallel cumsum over t (fp32): g [B=64, T=256, H=1024] bf16,
// t split into 4 chunks of 64. partial layout [b][c][f] fp32 (1 MB).
// ---------------------------------------------------------------------------
__global__ void scan_pass1(const u16* __restrict__ g, float* __restrict__ partial) {
    const int id = blockIdx.x * 256 + threadIdx.x;   // 262144
    const int f = id & 1023, c = (id >> 10) & 3, b = id >> 12;
    size_t base = (size_t)b * SEQ * HID + (size_t)c * 64 * HID + f;
    float s = 0.f;
#pragma unroll 4
    for (int t = 0; t < 64; ++t)
        s += b2f(g[base + (size_t)t * HID]);
    partial[id] = s;
}

__global__ void scan_pass2(u16* __restrict__ g, const float* __restrict__ partial) {
    const int id = blockIdx.x * 256 + threadIdx.x;
    const int f = id & 1023, c = (id >> 10) & 3, b = id >> 12;
    float run = 0.f;
    for (int cc = 0; cc < c; ++cc)
        run += partial[(b << 12) + (cc << 10) + f];
    size_t base = (size_t)b * SEQ * HID + (size_t)c * 64 * HID + f;
#pragma unroll 4
    for (int t = 0; t < 64; ++t) {
        size_t idx = base + (size_t)t * HID;
        run += b2f(g[idx]);
        g[idx] = f2b(run);
    }
}

// sum over t -> fp32 [B, H]
__global__ void sum_t(const u16* __restrict__ g, float* __restrict__ out) {
    const int id = blockIdx.x * 256 + threadIdx.x;  // 65536
    const int b = id >> 10, f = id & 1023;
    size_t base = (size_t)b * SEQ * HID + f;
    float acc = 0.f;
#pragma unroll 4
    for (int t = 0; t < SEQ; ++t)
        acc += b2f(g[base + (size_t)t * HID]);
    out[id] = acc;
}

// final fc, self-detected dtype on W/bias reads and the output write
__global__ void fc_final(const float* __restrict__ hf, const void* __restrict__ W,
                         const void* __restrict__ bias, void* __restrict__ out) {
    __shared__ float sh[HID];
    const int fp32 = is_fp32((const u16*)W);
    const int b = blockIdx.x, o = threadIdx.x;      // 64 blocks x 128 threads
    for (int k = o; k < HID; k += 128) sh[k] = hf[(size_t)b * HID + k];
    __syncthreads();
    float acc;
    if (fp32) {
        acc = ((const float*)bias)[o];
        for (int k = 0; k < HID; ++k)
            acc += sh[k] * ((const float*)W)[(size_t)k * OUTDIM + o];
        ((float*)out)[b * OUTDIM + o] = acc;
    } else {
        acc = b2f(((const u16*)bias)[o]);
        for (int k = 0; k < HID; ++k)
            acc += sh[k] * b2f(((const u16*)W)[(size_t)k * OUTDIM + o]);
        ((u16*)out)[b * OUTDIM + o] = f2b(acc);
    }
}

// ---------------------------------------------------------------------------
extern "C" void kernel_launch(void* const* d_in, const int* in_sizes, int n_in,
                              void* d_out, int out_size, void* d_ws, size_t ws_size,
                              hipStream_t stream) {
    const void* x      = d_in[0];
    const void* l0_Win = d_in[1];
    const void* l0_bin = d_in[2];
    const void* l0_Wh  = d_in[3];
    const void* l0_bh  = d_in[4];
    const void* l0_Wt  = d_in[5];
    const void* l0_bt  = d_in[6];
    const void* l1_Win = d_in[7];
    const void* l1_bin = d_in[8];
    const void* l1_Wh  = d_in[9];
    const void* l1_bh  = d_in[10];
    const void* l1_Wt  = d_in[11];
    const void* l1_bt  = d_in[12];
    const void* fc_W   = d_in[13];
    const void* fc_b   = d_in[14];

    char* ws = (char*)d_ws;
    u16* Pa = (u16*)(ws);                       // 32 MB
    u16* Pb = (u16*)(ws + 33554432);            // 32 MB; xc at its base; scan partial reuses it
    u16* xc = Pb;                               // [16384,128] clean bf16 x
    u16* tW = (u16*)(ws + 67108864);
    u16* tWin0 = tW;                  // [1024,128]
    u16* tWt00 = tWin0 + 131072;      // each [1024,1024]
    u16* tWt01 = tWt00 + 1048576;
    u16* tWh00 = tWt01 + 1048576;
    u16* tWh01 = tWh00 + 1048576;
    u16* tWin1 = tWh01 + 1048576;
    u16* tWt10 = tWin1 + 1048576;
    u16* tWt11 = tWt10 + 1048576;
    u16* tWh10 = tWt11 + 1048576;
    u16* tWh11 = tWh10 + 1048576;
    u16* smallb = tWh11 + 1048576;    // bias copies
    u16* binc0 = smallb;              // 1024
    u16* bhc0  = binc0 + 1024;        // 2048
    u16* btc0  = bhc0 + 2048;         // 2048
    u16* binc1 = btc0 + 2048;         // 1024
    u16* bhc1  = binc1 + 1024;        // 2048
    u16* btc1  = bhc1 + 2048;         // 2048
    float* hfinal = (float*)Pa;       // [64,1024] fp32, Pa dead by then

    const long DD = (long)HID * HID;
    PrepList L;
    // transposes (z 0..9)
    L.s[0] = l0_Win; L.d[0] = tWin0; L.R[0] = INDIM; L.Cc[0] = HID; L.off[0] = 0;
    L.s[1] = l0_Wt;  L.d[1] = tWt00; L.R[1] = HID;   L.Cc[1] = HID; L.off[1] = 0;
    L.s[2] = l0_Wt;  L.d[2] = tWt01; L.R[2] = HID;   L.Cc[2] = HID; L.off[2] = DD;
    L.s[3] = l0_Wh;  L.d[3] = tWh00; L.R[3] = HID;   L.Cc[3] = HID; L.off[3] = 0;
    L.s[4] = l0_Wh;  L.d[4] = tWh01; L.R[4] = HID;   L.Cc[4] = HID; L.off[4] = DD;
    L.s[5] = l1_Win; L.d[5] = tWin1; L.R[5] = HID;   L.Cc[5] = HID; L.off[5] = 0;
    L.s[6] = l1_Wt;  L.d[6] = tWt10; L.R[6] = HID;   L.Cc[6] = HID; L.off[6] = 0;
    L.s[7] = l1_Wt;  L.d[7] = tWt11; L.R[7] = HID;   L.Cc[7] = HID; L.off[7] = DD;
    L.s[8] = l1_Wh;  L.d[8] = tWh10; L.R[8] = HID;   L.Cc[8] = HID; L.off[8] = 0;
    L.s[9] = l1_Wh;  L.d[9] = tWh11; L.R[9] = HID;   L.Cc[9] = HID; L.off[9] = DD;
    // converts (z 10..16): R = elem count
    L.s[10] = x;      L.d[10] = xc;    L.R[10] = MROWS * INDIM; L.Cc[10] = 0; L.off[10] = 0;
    L.s[11] = l0_bin; L.d[11] = binc0; L.R[11] = HID;     L.Cc[11] = 0; L.off[11] = 0;
    L.s[12] = l0_bh;  L.d[12] = bhc0;  L.R[12] = 2 * HID; L.Cc[12] = 0; L.off[12] = 0;
    L.s[13] = l0_bt;  L.d[13] = btc0;  L.R[13] = 2 * HID; L.Cc[13] = 0; L.off[13] = 0;
    L.s[14] = l1_bin; L.d[14] = binc1; L.R[14] = HID;     L.Cc[14] = 0; L.off[14] = 0;
    L.s[15] = l1_bh;  L.d[15] = bhc1;  L.R[15] = 2 * HID; L.Cc[15] = 0; L.off[15] = 0;
    L.s[16] = l1_bt;  L.d[16] = btc1;  L.R[16] = 2 * HID; L.Cc[16] = 0; L.off[16] = 0;
    L.probe = (const u16*)l0_Wh;

    prep_all<<<dim3(32, 32, 17), dim3(32, 8), 0, stream>>>(L);

    // ---- layer 0 ----
    gemm128<<<dim3(8, 128), 256, 0, stream>>>(xc, tWin0, binc0, Pa, MROWS, HID, INDIM);
    gemm_hw<<<dim3(16, 128), 256, 0, stream>>>(Pa, tWt00, tWh00, btc0, bhc0, Pb, MROWS, HID, HID);
    gemm_hw<<<dim3(16, 128), 256, 0, stream>>>(Pb, tWt01, tWh01, btc0 + HID, bhc0 + HID, Pa, MROWS, HID, HID);
    // cumsum over t on Pa; partial sums live in dead Pb
    scan_pass1<<<1024, 256, 0, stream>>>(Pa, (float*)Pb);
    scan_pass2<<<1024, 256, 0, stream>>>(Pa, (const float*)Pb);   // Pa = y0

    // ---- layer 1 ----
    gemm64n<<<dim3(16, 128), 256, 0, stream>>>(Pa, tWin1, binc1, Pb, MROWS, HID, HID);
    gemm_hw<<<dim3(16, 128), 256, 0, stream>>>(Pb, tWt10, tWh10, btc1, bhc1, Pa, MROWS, HID, HID);
    gemm_hw<<<dim3(16, 128), 256, 0, stream>>>(Pa, tWt11, tWh11, btc1 + HID, bhc1 + HID, Pb, MROWS, HID, HID);

    // ---- tail ----
    sum_t<<<256, 256, 0, stream>>>(Pb, hfinal);
    fc_final<<<64, 128, 0, stream>>>(hfinal, fc_W, fc_b, d_out);
}

// Round 10
// 540.741 us; speedup vs baseline: 1.0269x; 1.0269x over previous
//
#include <hip/hip_runtime.h>

typedef unsigned short u16;
typedef unsigned int u32;
typedef __bf16 bf16x8 __attribute__((ext_vector_type(8)));
typedef float floatx4 __attribute__((ext_vector_type(4)));

#define HID 1024
#define BATCH 64
#define SEQ 256
#define INDIM 128
#define OUTDIM 128
#define MROWS (BATCH*SEQ)   // 16384

__device__ __forceinline__ float b2f(u16 u) {
    union { u32 u; float f; } v; v.u = ((u32)u) << 16; return v.f;
}
__device__ __forceinline__ u16 f2b(float f) {
    union { float f; u32 u; } v; v.f = f;
    u32 x = v.u;
    x += 0x7fffu + ((x >> 16) & 1u);
    return (u16)(x >> 16);
}
__device__ __forceinline__ float sigm(float x) { return 1.f / (1.f + __expf(-x)); }
__device__ __forceinline__ float tanh_f(float x) { return 2.f / (1.f + __expf(-2.f * x)) - 1.f; }

__device__ __forceinline__ void gld16(const u16* g, u16* l) {
    __builtin_amdgcn_global_load_lds(
        (const __attribute__((address_space(1))) void*)g,
        (__attribute__((address_space(3))) void*)l, 16, 0, 0);
}

// ---------------------------------------------------------------------------
// inline dtype detect: probe is l0_Wh (uniform ±1/32). bf16 -> exp field
// <= 121 always. fp32 misread -> ~50%/sample exp>=127; 64 samples -> certain.
// ---------------------------------------------------------------------------
__device__ __forceinline__ int is_fp32(const u16* probe) {
    const int lane = threadIdx.x & 63;
    const int e = (probe[lane * 7] >> 7) & 0xff;
    return __ballot(e >= 127) != 0ULL;
}

// ---------------------------------------------------------------------------
// ONE prep dispatch: z 0..9 transpose weights [R,C]->[C,R] (+elem offset for
// depth-1 slices); z 10..16 convert x + 6 bias vectors. Dtype self-detected.
// ---------------------------------------------------------------------------
struct PrepList {
    const void* s[17];
    u16*        d[17];
    int         R[17];      // transpose: rows; convert: elem count
    int         Cc[17];
    long        off[17];
    const u16*  probe;
};

__global__ void prep_all(PrepList L) {
    const int fp32 = is_fp32(L.probe);
    const int z = blockIdx.z;
    const void* src = L.s[z];
    u16*        dst = L.d[z];
    if (z >= 10) {   // convert, grid-stride over n
        const int n = L.R[z];
        const int tid = threadIdx.y * 32 + threadIdx.x;
        const int blk = blockIdx.y * 32 + blockIdx.x;
        const int stride = 1024 * 256;
        for (int i = blk * 256 + tid; i < n; i += stride) {
            u16 o;
            if (fp32) o = f2b(((const float*)src)[i]);
            else      o = ((const u16*)src)[i];
            dst[i] = o;
        }
        return;
    }
    const int R  = L.R[z];
    const int Cc = L.Cc[z];
    const long zo = L.off[z];
    const int tr = blockIdx.y * 32, tc = blockIdx.x * 32;
    if (tr >= R || tc >= Cc) return;           // block-uniform
    __align__(16) __shared__ u16 t[32][33];
    const int tx = threadIdx.x, ty = threadIdx.y;   // (32,8)
#pragma unroll
    for (int i = 0; i < 4; ++i) {
        const int r = ty + i * 8;
        const long e = zo + (long)(tr + r) * Cc + tc + tx;
        u16 v;
        if (fp32) v = f2b(((const float*)src)[e]);
        else      v = ((const u16*)src)[e];
        t[r][tx] = v;
    }
    __syncthreads();
#pragma unroll
    for (int i = 0; i < 4; ++i) {
        const int r = ty + i * 8;
        dst[(size_t)(tc + r) * R + tr + tx] = t[tx][r];
    }
}

// ---------------------------------------------------------------------------
// XCD-aware block remap (1024-block BN=128 grids): lin&7 -> XCD, each XCD a
// contiguous 16-m-tile strip x all 8 n-tiles (A strip = 4 MB = one L2).
// ---------------------------------------------------------------------------
__device__ __forceinline__ void tile_swizzle(int& m0, int& n0) {
    const int lin = blockIdx.y * gridDim.x + blockIdx.x;  // 0..1023
    const int xcd = lin & 7;
    const int loc = lin >> 3;
    m0 = (xcd * 16 + (loc & 15)) * 128;
    n0 = (loc >> 4) * 128;
}

// ---------------------------------------------------------------------------
// 128x128-tile bf16 MFMA GEMM, BK=64, XOR-swizzled global_load_lds staging,
// bias epilogue. 2 blocks/CU. (r6 config — best timed total)
// A: [M,K] row-major bf16.  BT: [N,K] row-major (B transposed). C = A@B + bias.
// ---------------------------------------------------------------------------
__global__ __launch_bounds__(256, 2) void gemm128(
    const u16* __restrict__ A, const u16* __restrict__ BT,
    const u16* __restrict__ bias, u16* __restrict__ C,
    int M, int N, int K)
{
    __align__(16) __shared__ u16 As[128 * 64];
    __align__(16) __shared__ u16 Bs[128 * 64];

    const int tid  = threadIdx.x;
    const int lane = tid & 63;
    const int wid  = tid >> 6;
    const int wr   = wid >> 1;
    const int wc   = wid & 1;

    int m0, n0;
    tile_swizzle(m0, n0);

    floatx4 acc[4][4] = {};

    const int srow = lane >> 3;
    const int scol = 8 * ((lane & 7) ^ (lane >> 3));
    const int cb   = wid * 4;
    const u16* Ag[4]; const u16* Bg[4];
    u16 *Al[4], *Bl[4];
#pragma unroll
    for (int j = 0; j < 4; ++j) {
        const int c = cb + j;
        const int r = c * 8 + srow;
        Ag[j] = A  + (size_t)(m0 + r) * K + scol;
        Bg[j] = BT + (size_t)(n0 + r) * K + scol;
        Al[j] = As + c * 512;
        Bl[j] = Bs + c * 512;
    }

    const int quad = lane >> 4;
    const int l16  = lane & 15;
    const int swz  = l16 & 7;

    const int nk = K >> 6;
    for (int kt = 0; kt < nk; ++kt) {
        __syncthreads();
#pragma unroll
        for (int j = 0; j < 4; ++j) {
            gld16(Ag[j], Al[j]);  gld16(Bg[j], Bl[j]);
            Ag[j] += 64; Bg[j] += 64;
        }
        __syncthreads();

#pragma unroll
        for (int kk = 0; kk < 2; ++kk) {
            const int slot = ((kk * 4 + quad) ^ swz) * 8;
            bf16x8 af[4], bfr[4];
#pragma unroll
            for (int i = 0; i < 4; ++i) {
                af[i]  = *(const bf16x8*)(As + (wr * 64 + i * 16 + l16) * 64 + slot);
                bfr[i] = *(const bf16x8*)(Bs + (wc * 64 + i * 16 + l16) * 64 + slot);
            }
#pragma unroll
            for (int i = 0; i < 4; ++i)
#pragma unroll
                for (int j = 0; j < 4; ++j)
                    acc[i][j] = __builtin_amdgcn_mfma_f32_16x16x32_bf16(af[i], bfr[j], acc[i][j], 0, 0, 0);
        }
    }

#pragma unroll
    for (int i = 0; i < 4; ++i) {
        const int rowb = m0 + wr * 64 + i * 16 + quad * 4;
#pragma unroll
        for (int j = 0; j < 4; ++j) {
            const int col = n0 + wc * 64 + j * 16 + l16;
            const float bv = b2f(bias[col]);
#pragma unroll
            for (int r = 0; r < 4; ++r)
                C[(size_t)(rowb + r) * N + col] = f2b(acc[i][j][r] + bv);
        }
    }
}

// ---------------------------------------------------------------------------
// Fused highway GEMM (r6 config — traffic-minimal fat tile): BM=128, BN=128
// dual-gate (each block covers 128 t-cols AND 128 h-cols), BK=64, wave-tile
// 64x64, XOR-swizzled LDS (48 KB), XCD remap, 2 blocks/CU.
// epilogue h_new = h_old + sig(t)*(tanh(h)-h_old), h_old re-read from A.
// ---------------------------------------------------------------------------
__global__ __launch_bounds__(256, 2) void gemm_hw(
    const u16* __restrict__ A,      // [M,K] = h
    const u16* __restrict__ WtT,    // [N,K]
    const u16* __restrict__ WhT,    // [N,K]
    const u16* __restrict__ bt, const u16* __restrict__ bh,
    u16* __restrict__ Hout,
    int M, int N, int K)
{
    __align__(16) __shared__ u16 As [128 * 64];
    __align__(16) __shared__ u16 Bts[128 * 64];
    __align__(16) __shared__ u16 Bhs[128 * 64];

    const int tid  = threadIdx.x;
    const int lane = tid & 63;
    const int wid  = tid >> 6;
    const int wr   = wid >> 1;
    const int wc   = wid & 1;

    int m0, n0;
    tile_swizzle(m0, n0);

    floatx4 acct[4][4] = {};
    floatx4 acch[4][4] = {};

    const int srow = lane >> 3;
    const int scol = 8 * ((lane & 7) ^ (lane >> 3));
    const int cb   = wid * 4;
    const u16* Ag[4]; const u16* Tg[4]; const u16* Hg[4];
    u16 *Al[4], *Tl[4], *Hl[4];
#pragma unroll
    for (int j = 0; j < 4; ++j) {
        const int c = cb + j;
        const int r = c * 8 + srow;
        Ag[j] = A   + (size_t)(m0 + r) * K + scol;
        Tg[j] = WtT + (size_t)(n0 + r) * K + scol;
        Hg[j] = WhT + (size_t)(n0 + r) * K + scol;
        Al[j] = As  + c * 512;
        Tl[j] = Bts + c * 512;
        Hl[j] = Bhs + c * 512;
    }

    const int quad = lane >> 4;
    const int l16  = lane & 15;
    const int swz  = l16 & 7;

    const int nk = K >> 6;
    for (int kt = 0; kt < nk; ++kt) {
        __syncthreads();
#pragma unroll
        for (int j = 0; j < 4; ++j) {
            gld16(Ag[j], Al[j]);  gld16(Tg[j], Tl[j]);  gld16(Hg[j], Hl[j]);
            Ag[j] += 64; Tg[j] += 64; Hg[j] += 64;
        }
        __syncthreads();

#pragma unroll
        for (int kk = 0; kk < 2; ++kk) {
            const int slot = ((kk * 4 + quad) ^ swz) * 8;
            bf16x8 af[4], btf[4], bhf[4];
#pragma unroll
            for (int i = 0; i < 4; ++i) {
                af[i]  = *(const bf16x8*)(As  + (wr * 64 + i * 16 + l16) * 64 + slot);
                btf[i] = *(const bf16x8*)(Bts + (wc * 64 + i * 16 + l16) * 64 + slot);
                bhf[i] = *(const bf16x8*)(Bhs + (wc * 64 + i * 16 + l16) * 64 + slot);
            }
#pragma unroll
            for (int i = 0; i < 4; ++i)
#pragma unroll
                for (int j = 0; j < 4; ++j) {
                    acct[i][j] = __builtin_amdgcn_mfma_f32_16x16x32_bf16(af[i], btf[j], acct[i][j], 0, 0, 0);
                    acch[i][j] = __builtin_amdgcn_mfma_f32_16x16x32_bf16(af[i], bhf[j], acch[i][j], 0, 0, 0);
                }
        }
    }

#pragma unroll
    for (int i = 0; i < 4; ++i) {
        const int rowb = m0 + wr * 64 + i * 16 + quad * 4;
#pragma unroll
        for (int j = 0; j < 4; ++j) {
            const int col = n0 + wc * 64 + j * 16 + l16;
            const float btv = b2f(bt[col]);
            const float bhv = b2f(bh[col]);
#pragma unroll
            for (int r = 0; r < 4; ++r) {
                const size_t idx = (size_t)(rowb + r) * N + col;
                const float hold = b2f(A[idx]);
                const float tg = sigm(acct[i][j][r] + btv);
                const float hl = tanh_f(acch[i][j][r] + bhv);
                Hout[idx] = f2b(hold + tg * (hl - hold));
            }
        }
    }
}

// ---------------------------------------------------------------------------
// two-pass parallel cumsum over t (fp32): g [B=64, T=256, H=1024] bf16,
// t split into 4 chunks of 64. partial layout [b][c][f] fp32 (1 MB).
// ---------------------------------------------------------------------------
__global__ void scan_pass1(const u16* __restrict__ g, float* __restrict__ partial) {
    const int id = blockIdx.x * 256 + threadIdx.x;   // 262144
    const int f = id & 1023, c = (id >> 10) & 3, b = id >> 12;
    size_t base = (size_t)b * SEQ * HID + (size_t)c * 64 * HID + f;
    float s = 0.f;
#pragma unroll 4
    for (int t = 0; t < 64; ++t)
        s += b2f(g[base + (size_t)t * HID]);
    partial[id] = s;
}

__global__ void scan_pass2(u16* __restrict__ g, const float* __restrict__ partial) {
    const int id = blockIdx.x * 256 + threadIdx.x;
    const int f = id & 1023, c = (id >> 10) & 3, b = id >> 12;
    float run = 0.f;
    for (int cc = 0; cc < c; ++cc)
        run += partial[(b << 12) + (cc << 10) + f];
    size_t base = (size_t)b * SEQ * HID + (size_t)c * 64 * HID + f;
#pragma unroll 4
    for (int t = 0; t < 64; ++t) {
        size_t idx = base + (size_t)t * HID;
        run += b2f(g[idx]);
        g[idx] = f2b(run);
    }
}

// sum over t -> fp32 [B, H]
__global__ void sum_t(const u16* __restrict__ g, float* __restrict__ out) {
    const int id = blockIdx.x * 256 + threadIdx.x;  // 65536
    const int b = id >> 10, f = id & 1023;
    size_t base = (size_t)b * SEQ * HID + f;
    float acc = 0.f;
#pragma unroll 4
    for (int t = 0; t < SEQ; ++t)
        acc += b2f(g[base + (size_t)t * HID]);
    out[id] = acc;
}

// final fc, self-detected dtype on W/bias reads and the output write
__global__ void fc_final(const float* __restrict__ hf, const void* __restrict__ W,
                         const void* __restrict__ bias, void* __restrict__ out) {
    __shared__ float sh[HID];
    const int fp32 = is_fp32((const u16*)W);
    const int b = blockIdx.x, o = threadIdx.x;      // 64 blocks x 128 threads
    for (int k = o; k < HID; k += 128) sh[k] = hf[(size_t)b * HID + k];
    __syncthreads();
    float acc;
    if (fp32) {
        acc = ((const float*)bias)[o];
        for (int k = 0; k < HID; ++k)
            acc += sh[k] * ((const float*)W)[(size_t)k * OUTDIM + o];
        ((float*)out)[b * OUTDIM + o] = acc;
    } else {
        acc = b2f(((const u16*)bias)[o]);
        for (int k = 0; k < HID; ++k)
            acc += sh[k] * b2f(((const u16*)W)[(size_t)k * OUTDIM + o]);
        ((u16*)out)[b * OUTDIM + o] = f2b(acc);
    }
}

// ---------------------------------------------------------------------------
extern "C" void kernel_launch(void* const* d_in, const int* in_sizes, int n_in,
                              void* d_out, int out_size, void* d_ws, size_t ws_size,
                              hipStream_t stream) {
    const void* x      = d_in[0];
    const void* l0_Win = d_in[1];
    const void* l0_bin = d_in[2];
    const void* l0_Wh  = d_in[3];
    const void* l0_bh  = d_in[4];
    const void* l0_Wt  = d_in[5];
    const void* l0_bt  = d_in[6];
    const void* l1_Win = d_in[7];
    const void* l1_bin = d_in[8];
    const void* l1_Wh  = d_in[9];
    const void* l1_bh  = d_in[10];
    const void* l1_Wt  = d_in[11];
    const void* l1_bt  = d_in[12];
    const void* fc_W   = d_in[13];
    const void* fc_b   = d_in[14];

    char* ws = (char*)d_ws;
    u16* Pa = (u16*)(ws);                       // 32 MB
    u16* Pb = (u16*)(ws + 33554432);            // 32 MB; xc at its base; scan partial reuses it
    u16* xc = Pb;                               // [16384,128] clean bf16 x
    u16* tW = (u16*)(ws + 67108864);
    u16* tWin0 = tW;                  // [1024,128]
    u16* tWt00 = tWin0 + 131072;      // each [1024,1024]
    u16* tWt01 = tWt00 + 1048576;
    u16* tWh00 = tWt01 + 1048576;
    u16* tWh01 = tWh00 + 1048576;
    u16* tWin1 = tWh01 + 1048576;
    u16* tWt10 = tWin1 + 1048576;
    u16* tWt11 = tWt10 + 1048576;
    u16* tWh10 = tWt11 + 1048576;
    u16* tWh11 = tWh10 + 1048576;
    u16* smallb = tWh11 + 1048576;    // bias copies
    u16* binc0 = smallb;              // 1024
    u16* bhc0  = binc0 + 1024;        // 2048
    u16* btc0  = bhc0 + 2048;         // 2048
    u16* binc1 = btc0 + 2048;         // 1024
    u16* bhc1  = binc1 + 1024;        // 2048
    u16* btc1  = bhc1 + 2048;         // 2048
    float* hfinal = (float*)Pa;       // [64,1024] fp32, Pa dead by then

    const long DD = (long)HID * HID;
    PrepList L;
    // transposes (z 0..9)
    L.s[0] = l0_Win; L.d[0] = tWin0; L.R[0] = INDIM; L.Cc[0] = HID; L.off[0] = 0;
    L.s[1] = l0_Wt;  L.d[1] = tWt00; L.R[1] = HID;   L.Cc[1] = HID; L.off[1] = 0;
    L.s[2] = l0_Wt;  L.d[2] = tWt01; L.R[2] = HID;   L.Cc[2] = HID; L.off[2] = DD;
    L.s[3] = l0_Wh;  L.d[3] = tWh00; L.R[3] = HID;   L.Cc[3] = HID; L.off[3] = 0;
    L.s[4] = l0_Wh;  L.d[4] = tWh01; L.R[4] = HID;   L.Cc[4] = HID; L.off[4] = DD;
    L.s[5] = l1_Win; L.d[5] = tWin1; L.R[5] = HID;   L.Cc[5] = HID; L.off[5] = 0;
    L.s[6] = l1_Wt;  L.d[6] = tWt10; L.R[6] = HID;   L.Cc[6] = HID; L.off[6] = 0;
    L.s[7] = l1_Wt;  L.d[7] = tWt11; L.R[7] = HID;   L.Cc[7] = HID; L.off[7] = DD;
    L.s[8] = l1_Wh;  L.d[8] = tWh10; L.R[8] = HID;   L.Cc[8] = HID; L.off[8] = 0;
    L.s[9] = l1_Wh;  L.d[9] = tWh11; L.R[9] = HID;   L.Cc[9] = HID; L.off[9] = DD;
    // converts (z 10..16): R = elem count
    L.s[10] = x;      L.d[10] = xc;    L.R[10] = MROWS * INDIM; L.Cc[10] = 0; L.off[10] = 0;
    L.s[11] = l0_bin; L.d[11] = binc0; L.R[11] = HID;     L.Cc[11] = 0; L.off[11] = 0;
    L.s[12] = l0_bh;  L.d[12] = bhc0;  L.R[12] = 2 * HID; L.Cc[12] = 0; L.off[12] = 0;
    L.s[13] = l0_bt;  L.d[13] = btc0;  L.R[13] = 2 * HID; L.Cc[13] = 0; L.off[13] = 0;
    L.s[14] = l1_bin; L.d[14] = binc1; L.R[14] = HID;     L.Cc[14] = 0; L.off[14] = 0;
    L.s[15] = l1_bh;  L.d[15] = bhc1;  L.R[15] = 2 * HID; L.Cc[15] = 0; L.off[15] = 0;
    L.s[16] = l1_bt;  L.d[16] = btc1;  L.R[16] = 2 * HID; L.Cc[16] = 0; L.off[16] = 0;
    L.probe = (const u16*)l0_Wh;

    prep_all<<<dim3(32, 32, 17), dim3(32, 8), 0, stream>>>(L);

    // ---- layer 0 ----
    gemm128<<<dim3(8, 128), 256, 0, stream>>>(xc, tWin0, binc0, Pa, MROWS, HID, INDIM);
    gemm_hw<<<dim3(8, 128), 256, 0, stream>>>(Pa, tWt00, tWh00, btc0, bhc0, Pb, MROWS, HID, HID);
    gemm_hw<<<dim3(8, 128), 256, 0, stream>>>(Pb, tWt01, tWh01, btc0 + HID, bhc0 + HID, Pa, MROWS, HID, HID);
    // cumsum over t on Pa; partial sums live in dead Pb
    scan_pass1<<<1024, 256, 0, stream>>>(Pa, (float*)Pb);
    scan_pass2<<<1024, 256, 0, stream>>>(Pa, (const float*)Pb);   // Pa = y0

    // ---- layer 1 ----
    gemm128<<<dim3(8, 128), 256, 0, stream>>>(Pa, tWin1, binc1, Pb, MROWS, HID, HID);
    gemm_hw<<<dim3(8, 128), 256, 0, stream>>>(Pb, tWt10, tWh10, btc1, bhc1, Pa, MROWS, HID, HID);
    gemm_hw<<<dim3(8, 128), 256, 0, stream>>>(Pa, tWt11, tWh11, btc1 + HID, bhc1 + HID, Pb, MROWS, HID, HID);

    // ---- tail ----
    sum_t<<<256, 256, 0, stream>>>(Pb, hfinal);
    fc_final<<<64, 128, 0, stream>>>(hfinal, fc_W, fc_b, d_out);
}

// Round 11
// 511.107 us; speedup vs baseline: 1.0865x; 1.0580x over previous
//
#include <hip/hip_runtime.h>

typedef unsigned short u16;
typedef unsigned int u32;
typedef __bf16 bf16x8 __attribute__((ext_vector_type(8)));
typedef float floatx4 __attribute__((ext_vector_type(4)));

#define HID 1024
#define BATCH 64
#define SEQ 256
#define INDIM 128
#define OUTDIM 128
#define MROWS (BATCH*SEQ)   // 16384

__device__ __forceinline__ float b2f(u16 u) {
    union { u32 u; float f; } v; v.u = ((u32)u) << 16; return v.f;
}
__device__ __forceinline__ u16 f2b(float f) {
    union { float f; u32 u; } v; v.f = f;
    u32 x = v.u;
    x += 0x7fffu + ((x >> 16) & 1u);
    return (u16)(x >> 16);
}
__device__ __forceinline__ float sigm(float x) { return 1.f / (1.f + __expf(-x)); }
__device__ __forceinline__ float tanh_f(float x) { return 2.f / (1.f + __expf(-2.f * x)) - 1.f; }

__device__ __forceinline__ void gld16(const u16* g, u16* l) {
    __builtin_amdgcn_global_load_lds(
        (const __attribute__((address_space(1))) void*)g,
        (__attribute__((address_space(3))) void*)l, 16, 0, 0);
}

// ---------------------------------------------------------------------------
// dtype detector (r6 form): l0_Wh uniform(-1/32,1/32); bf16 exp always <127,
// fp32-misread u16s hit exp>=127 w.p. ~0.5/sample. flag=1 -> inputs fp32.
// ---------------------------------------------------------------------------
__global__ void detect_dtype(const u16* __restrict__ w, int* __restrict__ flag) {
    __shared__ int s;
    if (threadIdx.x == 0) s = 0;
    __syncthreads();
    int bad = 0;
    for (int i = threadIdx.x; i < 4096; i += 256) {
        int e = (w[i] >> 7) & 0xff;
        if (e >= 127) bad = 1;
    }
    if (bad) atomicOr(&s, 1);
    __syncthreads();
    if (threadIdx.x == 0) *flag = s;
}

// inline self-detect for fc_final (fc_W uniform ±1/32, same bound)
__device__ __forceinline__ int is_fp32(const u16* probe) {
    const int lane = threadIdx.x & 63;
    const int e = (probe[lane * 7] >> 7) & 0xff;
    return __ballot(e >= 127) != 0ULL;
}

// ---------------------------------------------------------------------------
// convert 7 tensors (x + 6 bias vectors) to clean bf16 (r6 form)
// ---------------------------------------------------------------------------
struct CvtList { const void* s[7]; u16* d[7]; int n[7]; };

__global__ void convert7(CvtList C, const int* __restrict__ flag) {
    const int fp32 = *flag;
    const int z = blockIdx.y;
    const int n = C.n[z];
    const int stride = gridDim.x * 256;
    for (int i = blockIdx.x * 256 + threadIdx.x; i < n; i += stride) {
        u16 o;
        if (fp32) o = f2b(((const float*)C.s[z])[i]);
        else      o = ((const u16*)C.s[z])[i];
        C.d[z][i] = o;
    }
}

// ---------------------------------------------------------------------------
// transpose 10 weight matrices [R,C]->[C,R] bf16 out (r6 form)
// ---------------------------------------------------------------------------
struct TListO {
    const void* s[10];
    u16*        d[10];
    int         R[10];
    int         Cc[10];
    long        off[10];
};

__global__ void transpose10(TListO L, const int* __restrict__ flag) {
    const int fp32 = *flag;
    const int z = blockIdx.z;
    const void* src = L.s[z];
    u16*        dst = L.d[z];
    const int R  = L.R[z];
    const int Cc = L.Cc[z];
    const long zo = L.off[z];
    const int tr = blockIdx.y * 32, tc = blockIdx.x * 32;
    if (tr >= R || tc >= Cc) return;           // block-uniform
    __align__(16) __shared__ u16 t[32][33];
    const int tx = threadIdx.x, ty = threadIdx.y;   // (32,8)
#pragma unroll
    for (int i = 0; i < 4; ++i) {
        const int r = ty + i * 8;
        const long e = zo + (long)(tr + r) * Cc + tc + tx;
        u16 v;
        if (fp32) v = f2b(((const float*)src)[e]);
        else      v = ((const u16*)src)[e];
        t[r][tx] = v;
    }
    __syncthreads();
#pragma unroll
    for (int i = 0; i < 4; ++i) {
        const int r = ty + i * 8;
        dst[(size_t)(tc + r) * R + tr + tx] = t[tx][r];
    }
}

// ---------------------------------------------------------------------------
// XCD-aware block remap (1024-block BN=128 grids)
// ---------------------------------------------------------------------------
__device__ __forceinline__ void tile_swizzle(int& m0, int& n0) {
    const int lin = blockIdx.y * gridDim.x + blockIdx.x;  // 0..1023
    const int xcd = lin & 7;
    const int loc = lin >> 3;
    m0 = (xcd * 16 + (loc & 15)) * 128;
    n0 = (loc >> 4) * 128;
}

// ---------------------------------------------------------------------------
// 128x128-tile bf16 MFMA GEMM, BK=64, XOR-swizzled global_load_lds staging,
// bias epilogue, 2 blocks/CU. (r6 config — best timed total)
// ---------------------------------------------------------------------------
__global__ __launch_bounds__(256, 2) void gemm128(
    const u16* __restrict__ A, const u16* __restrict__ BT,
    const u16* __restrict__ bias, u16* __restrict__ C,
    int M, int N, int K)
{
    __align__(16) __shared__ u16 As[128 * 64];
    __align__(16) __shared__ u16 Bs[128 * 64];

    const int tid  = threadIdx.x;
    const int lane = tid & 63;
    const int wid  = tid >> 6;
    const int wr   = wid >> 1;
    const int wc   = wid & 1;

    int m0, n0;
    tile_swizzle(m0, n0);

    floatx4 acc[4][4] = {};

    const int srow = lane >> 3;
    const int scol = 8 * ((lane & 7) ^ (lane >> 3));
    const int cb   = wid * 4;
    const u16* Ag[4]; const u16* Bg[4];
    u16 *Al[4], *Bl[4];
#pragma unroll
    for (int j = 0; j < 4; ++j) {
        const int c = cb + j;
        const int r = c * 8 + srow;
        Ag[j] = A  + (size_t)(m0 + r) * K + scol;
        Bg[j] = BT + (size_t)(n0 + r) * K + scol;
        Al[j] = As + c * 512;
        Bl[j] = Bs + c * 512;
    }

    const int quad = lane >> 4;
    const int l16  = lane & 15;
    const int swz  = l16 & 7;

    const int nk = K >> 6;
    for (int kt = 0; kt < nk; ++kt) {
        __syncthreads();
#pragma unroll
        for (int j = 0; j < 4; ++j) {
            gld16(Ag[j], Al[j]);  gld16(Bg[j], Bl[j]);
            Ag[j] += 64; Bg[j] += 64;
        }
        __syncthreads();

#pragma unroll
        for (int kk = 0; kk < 2; ++kk) {
            const int slot = ((kk * 4 + quad) ^ swz) * 8;
            bf16x8 af[4], bfr[4];
#pragma unroll
            for (int i = 0; i < 4; ++i) {
                af[i]  = *(const bf16x8*)(As + (wr * 64 + i * 16 + l16) * 64 + slot);
                bfr[i] = *(const bf16x8*)(Bs + (wc * 64 + i * 16 + l16) * 64 + slot);
            }
#pragma unroll
            for (int i = 0; i < 4; ++i)
#pragma unroll
                for (int j = 0; j < 4; ++j)
                    acc[i][j] = __builtin_amdgcn_mfma_f32_16x16x32_bf16(af[i], bfr[j], acc[i][j], 0, 0, 0);
        }
    }

#pragma unroll
    for (int i = 0; i < 4; ++i) {
        const int rowb = m0 + wr * 64 + i * 16 + quad * 4;
#pragma unroll
        for (int j = 0; j < 4; ++j) {
            const int col = n0 + wc * 64 + j * 16 + l16;
            const float bv = b2f(bias[col]);
#pragma unroll
            for (int r = 0; r < 4; ++r)
                C[(size_t)(rowb + r) * N + col] = f2b(acc[i][j][r] + bv);
        }
    }
}

// ---------------------------------------------------------------------------
// Fused highway GEMM (r6 config): BM=128, BN=128 dual-gate, BK=64, wave-tile
// 64x64, 48 KB LDS, 2 blocks/CU. h_new = h_old + sig(t)*(tanh(h)-h_old).
// ---------------------------------------------------------------------------
__global__ __launch_bounds__(256, 2) void gemm_hw(
    const u16* __restrict__ A,      // [M,K] = h
    const u16* __restrict__ WtT,    // [N,K]
    const u16* __restrict__ WhT,    // [N,K]
    const u16* __restrict__ bt, const u16* __restrict__ bh,
    u16* __restrict__ Hout,
    int M, int N, int K)
{
    __align__(16) __shared__ u16 As [128 * 64];
    __align__(16) __shared__ u16 Bts[128 * 64];
    __align__(16) __shared__ u16 Bhs[128 * 64];

    const int tid  = threadIdx.x;
    const int lane = tid & 63;
    const int wid  = tid >> 6;
    const int wr   = wid >> 1;
    const int wc   = wid & 1;

    int m0, n0;
    tile_swizzle(m0, n0);

    floatx4 acct[4][4] = {};
    floatx4 acch[4][4] = {};

    const int srow = lane >> 3;
    const int scol = 8 * ((lane & 7) ^ (lane >> 3));
    const int cb   = wid * 4;
    const u16* Ag[4]; const u16* Tg[4]; const u16* Hg[4];
    u16 *Al[4], *Tl[4], *Hl[4];
#pragma unroll
    for (int j = 0; j < 4; ++j) {
        const int c = cb + j;
        const int r = c * 8 + srow;
        Ag[j] = A   + (size_t)(m0 + r) * K + scol;
        Tg[j] = WtT + (size_t)(n0 + r) * K + scol;
        Hg[j] = WhT + (size_t)(n0 + r) * K + scol;
        Al[j] = As  + c * 512;
        Tl[j] = Bts + c * 512;
        Hl[j] = Bhs + c * 512;
    }

    const int quad = lane >> 4;
    const int l16  = lane & 15;
    const int swz  = l16 & 7;

    const int nk = K >> 6;
    for (int kt = 0; kt < nk; ++kt) {
        __syncthreads();
#pragma unroll
        for (int j = 0; j < 4; ++j) {
            gld16(Ag[j], Al[j]);  gld16(Tg[j], Tl[j]);  gld16(Hg[j], Hl[j]);
            Ag[j] += 64; Tg[j] += 64; Hg[j] += 64;
        }
        __syncthreads();

#pragma unroll
        for (int kk = 0; kk < 2; ++kk) {
            const int slot = ((kk * 4 + quad) ^ swz) * 8;
            bf16x8 af[4], btf[4], bhf[4];
#pragma unroll
            for (int i = 0; i < 4; ++i) {
                af[i]  = *(const bf16x8*)(As  + (wr * 64 + i * 16 + l16) * 64 + slot);
                btf[i] = *(const bf16x8*)(Bts + (wc * 64 + i * 16 + l16) * 64 + slot);
                bhf[i] = *(const bf16x8*)(Bhs + (wc * 64 + i * 16 + l16) * 64 + slot);
            }
#pragma unroll
            for (int i = 0; i < 4; ++i)
#pragma unroll
                for (int j = 0; j < 4; ++j) {
                    acct[i][j] = __builtin_amdgcn_mfma_f32_16x16x32_bf16(af[i], btf[j], acct[i][j], 0, 0, 0);
                    acch[i][j] = __builtin_amdgcn_mfma_f32_16x16x32_bf16(af[i], bhf[j], acch[i][j], 0, 0, 0);
                }
        }
    }

#pragma unroll
    for (int i = 0; i < 4; ++i) {
        const int rowb = m0 + wr * 64 + i * 16 + quad * 4;
#pragma unroll
        for (int j = 0; j < 4; ++j) {
            const int col = n0 + wc * 64 + j * 16 + l16;
            const float btv = b2f(bt[col]);
            const float bhv = b2f(bh[col]);
#pragma unroll
            for (int r = 0; r < 4; ++r) {
                const size_t idx = (size_t)(rowb + r) * N + col;
                const float hold = b2f(A[idx]);
                const float tg = sigm(acct[i][j][r] + btv);
                const float hl = tanh_f(acch[i][j][r] + bhv);
                Hout[idx] = f2b(hold + tg * (hl - hold));
            }
        }
    }
}

// ---------------------------------------------------------------------------
// Final-stage highway GEMM: identical K-loop, but the epilogue sums h_new over
// its 128 rows (in-register + shfl-xor over quad lanes) and atomicAdds fp32
// into hsum[b*HID+col] instead of writing the 32 MB Hout. b = m0>>8 is valid:
// a 128-row m-tile never straddles a batch's 256-row span.
// ---------------------------------------------------------------------------
__global__ __launch_bounds__(256, 2) void gemm_hw_sum(
    const u16* __restrict__ A,      // [M,K] = h
    const u16* __restrict__ WtT,    // [N,K]
    const u16* __restrict__ WhT,    // [N,K]
    const u16* __restrict__ bt, const u16* __restrict__ bh,
    float* __restrict__ hsum,       // [BATCH, HID] fp32, pre-zeroed
    int M, int N, int K)
{
    __align__(16) __shared__ u16 As [128 * 64];
    __align__(16) __shared__ u16 Bts[128 * 64];
    __align__(16) __shared__ u16 Bhs[128 * 64];

    const int tid  = threadIdx.x;
    const int lane = tid & 63;
    const int wid  = tid >> 6;
    const int wr   = wid >> 1;
    const int wc   = wid & 1;

    int m0, n0;
    tile_swizzle(m0, n0);

    floatx4 acct[4][4] = {};
    floatx4 acch[4][4] = {};

    const int srow = lane >> 3;
    const int scol = 8 * ((lane & 7) ^ (lane >> 3));
    const int cb   = wid * 4;
    const u16* Ag[4]; const u16* Tg[4]; const u16* Hg[4];
    u16 *Al[4], *Tl[4], *Hl[4];
#pragma unroll
    for (int j = 0; j < 4; ++j) {
        const int c = cb + j;
        const int r = c * 8 + srow;
        Ag[j] = A   + (size_t)(m0 + r) * K + scol;
        Tg[j] = WtT + (size_t)(n0 + r) * K + scol;
        Hg[j] = WhT + (size_t)(n0 + r) * K + scol;
        Al[j] = As  + c * 512;
        Tl[j] = Bts + c * 512;
        Hl[j] = Bhs + c * 512;
    }

    const int quad = lane >> 4;
    const int l16  = lane & 15;
    const int swz  = l16 & 7;

    const int nk = K >> 6;
    for (int kt = 0; kt < nk; ++kt) {
        __syncthreads();
#pragma unroll
        for (int j = 0; j < 4; ++j) {
            gld16(Ag[j], Al[j]);  gld16(Tg[j], Tl[j]);  gld16(Hg[j], Hl[j]);
            Ag[j] += 64; Tg[j] += 64; Hg[j] += 64;
        }
        __syncthreads();

#pragma unroll
        for (int kk = 0; kk < 2; ++kk) {
            const int slot = ((kk * 4 + quad) ^ swz) * 8;
            bf16x8 af[4], btf[4], bhf[4];
#pragma unroll
            for (int i = 0; i < 4; ++i) {
                af[i]  = *(const bf16x8*)(As  + (wr * 64 + i * 16 + l16) * 64 + slot);
                btf[i] = *(const bf16x8*)(Bts + (wc * 64 + i * 16 + l16) * 64 + slot);
                bhf[i] = *(const bf16x8*)(Bhs + (wc * 64 + i * 16 + l16) * 64 + slot);
            }
#pragma unroll
            for (int i = 0; i < 4; ++i)
#pragma unroll
                for (int j = 0; j < 4; ++j) {
                    acct[i][j] = __builtin_amdgcn_mfma_f32_16x16x32_bf16(af[i], btf[j], acct[i][j], 0, 0, 0);
                    acch[i][j] = __builtin_amdgcn_mfma_f32_16x16x32_bf16(af[i], bhf[j], acch[i][j], 0, 0, 0);
                }
        }
    }

    const int b = m0 >> 8;
#pragma unroll
    for (int j = 0; j < 4; ++j) {
        const int col = n0 + wc * 64 + j * 16 + l16;
        const float btv = b2f(bt[col]);
        const float bhv = b2f(bh[col]);
        float colsum = 0.f;
#pragma unroll
        for (int i = 0; i < 4; ++i) {
            const int rowb = m0 + wr * 64 + i * 16 + quad * 4;
#pragma unroll
            for (int r = 0; r < 4; ++r) {
                const size_t idx = (size_t)(rowb + r) * N + col;
                const float hold = b2f(A[idx]);
                const float tg = sigm(acct[i][j][r] + btv);
                const float hl = tanh_f(acch[i][j][r] + bhv);
                colsum += hold + tg * (hl - hold);
            }
        }
        // reduce over quad lanes (lane ^16, ^32 share l16/wc within the wave)
        colsum += __shfl_xor(colsum, 16, 64);
        colsum += __shfl_xor(colsum, 32, 64);
        if (quad == 0)
            atomicAdd(&hsum[(size_t)b * HID + col], colsum);
    }
}

// zero the 256 KB hsum accumulator (ws is poisoned 0xAA before every call)
__global__ void zero_hf(float* __restrict__ p) {
    p[blockIdx.x * 256 + threadIdx.x] = 0.f;   // 256 blocks x 256 = 65536
}

// ---------------------------------------------------------------------------
// in-place cumsum over t (fp32 accumulate), r6 form: g [B=64,T=256,H=1024]
// ---------------------------------------------------------------------------
__global__ void cumsum_t(u16* g) {
    const int id = blockIdx.x * 256 + threadIdx.x;  // 65536 = B*H
    const int b = id >> 10, f = id & 1023;
    size_t base = (size_t)b * SEQ * HID + f;
    float acc = 0.f;
#pragma unroll 4
    for (int t = 0; t < SEQ; ++t) {
        size_t idx = base + (size_t)t * HID;
        acc += b2f(g[idx]);
        g[idx] = f2b(acc);
    }
}

// final fc, self-detected dtype on W/bias reads and the output write
__global__ void fc_final(const float* __restrict__ hf, const void* __restrict__ W,
                         const void* __restrict__ bias, void* __restrict__ out) {
    __shared__ float sh[HID];
    const int fp32 = is_fp32((const u16*)W);
    const int b = blockIdx.x, o = threadIdx.x;      // 64 blocks x 128 threads
    for (int k = o; k < HID; k += 128) sh[k] = hf[(size_t)b * HID + k];
    __syncthreads();
    float acc;
    if (fp32) {
        acc = ((const float*)bias)[o];
        for (int k = 0; k < HID; ++k)
            acc += sh[k] * ((const float*)W)[(size_t)k * OUTDIM + o];
        ((float*)out)[b * OUTDIM + o] = acc;
    } else {
        acc = b2f(((const u16*)bias)[o]);
        for (int k = 0; k < HID; ++k)
            acc += sh[k] * b2f(((const u16*)W)[(size_t)k * OUTDIM + o]);
        ((u16*)out)[b * OUTDIM + o] = f2b(acc);
    }
}

// ---------------------------------------------------------------------------
extern "C" void kernel_launch(void* const* d_in, const int* in_sizes, int n_in,
                              void* d_out, int out_size, void* d_ws, size_t ws_size,
                              hipStream_t stream) {
    const void* x      = d_in[0];
    const void* l0_Win = d_in[1];
    const void* l0_bin = d_in[2];
    const void* l0_Wh  = d_in[3];
    const void* l0_bh  = d_in[4];
    const void* l0_Wt  = d_in[5];
    const void* l0_bt  = d_in[6];
    const void* l1_Win = d_in[7];
    const void* l1_bin = d_in[8];
    const void* l1_Wh  = d_in[9];
    const void* l1_bh  = d_in[10];
    const void* l1_Wt  = d_in[11];
    const void* l1_bt  = d_in[12];
    const void* fc_W   = d_in[13];
    const void* fc_b   = d_in[14];

    char* ws = (char*)d_ws;
    u16* Pa = (u16*)(ws);                       // 32 MB
    u16* Pb = (u16*)(ws + 33554432);            // 32 MB; xc at its base; hfinal reuses it at tail
    u16* xc = Pb;                               // [16384,128] clean bf16 x
    u16* tW = (u16*)(ws + 67108864);
    u16* tWin0 = tW;                  // [1024,128]
    u16* tWt00 = tWin0 + 131072;      // each [1024,1024]
    u16* tWt01 = tWt00 + 1048576;
    u16* tWh00 = tWt01 + 1048576;
    u16* tWh01 = tWh00 + 1048576;
    u16* tWin1 = tWh01 + 1048576;
    u16* tWt10 = tWin1 + 1048576;
    u16* tWt11 = tWt10 + 1048576;
    u16* tWh10 = tWt11 + 1048576;
    u16* tWh11 = tWh10 + 1048576;
    u16* smallb = tWh11 + 1048576;    // bias copies
    u16* binc0 = smallb;              // 1024
    u16* bhc0  = binc0 + 1024;        // 2048
    u16* btc0  = bhc0 + 2048;         // 2048
    u16* binc1 = btc0 + 2048;         // 1024
    u16* bhc1  = binc1 + 1024;        // 2048
    u16* btc1  = bhc1 + 2048;         // 2048
    int* flag  = (int*)(btc1 + 2048);
    float* hfinal = (float*)Pb;       // [64,1024] fp32; Pb dead during final stage

    detect_dtype<<<1, 256, 0, stream>>>((const u16*)l0_Wh, flag);

    const long DD = (long)HID * HID;
    TListO L;
    L.s[0] = l0_Win; L.d[0] = tWin0; L.R[0] = INDIM; L.Cc[0] = HID; L.off[0] = 0;
    L.s[1] = l0_Wt;  L.d[1] = tWt00; L.R[1] = HID;   L.Cc[1] = HID; L.off[1] = 0;
    L.s[2] = l0_Wt;  L.d[2] = tWt01; L.R[2] = HID;   L.Cc[2] = HID; L.off[2] = DD;
    L.s[3] = l0_Wh;  L.d[3] = tWh00; L.R[3] = HID;   L.Cc[3] = HID; L.off[3] = 0;
    L.s[4] = l0_Wh;  L.d[4] = tWh01; L.R[4] = HID;   L.Cc[4] = HID; L.off[4] = DD;
    L.s[5] = l1_Win; L.d[5] = tWin1; L.R[5] = HID;   L.Cc[5] = HID; L.off[5] = 0;
    L.s[6] = l1_Wt;  L.d[6] = tWt10; L.R[6] = HID;   L.Cc[6] = HID; L.off[6] = 0;
    L.s[7] = l1_Wt;  L.d[7] = tWt11; L.R[7] = HID;   L.Cc[7] = HID; L.off[7] = DD;
    L.s[8] = l1_Wh;  L.d[8] = tWh10; L.R[8] = HID;   L.Cc[8] = HID; L.off[8] = 0;
    L.s[9] = l1_Wh;  L.d[9] = tWh11; L.R[9] = HID;   L.Cc[9] = HID; L.off[9] = DD;
    transpose10<<<dim3(32, 32, 10), dim3(32, 8), 0, stream>>>(L, flag);

    CvtList C7;
    C7.s[0] = x;      C7.d[0] = xc;    C7.n[0] = MROWS * INDIM;
    C7.s[1] = l0_bin; C7.d[1] = binc0; C7.n[1] = HID;
    C7.s[2] = l0_bh;  C7.d[2] = bhc0;  C7.n[2] = 2 * HID;
    C7.s[3] = l0_bt;  C7.d[3] = btc0;  C7.n[3] = 2 * HID;
    C7.s[4] = l1_bin; C7.d[4] = binc1; C7.n[4] = HID;
    C7.s[5] = l1_bh;  C7.d[5] = bhc1;  C7.n[5] = 2 * HID;
    C7.s[6] = l1_bt;  C7.d[6] = btc1;  C7.n[6] = 2 * HID;
    convert7<<<dim3(512, 7), 256, 0, stream>>>(C7, flag);

    // ---- layer 0 ----
    gemm128<<<dim3(8, 128), 256, 0, stream>>>(xc, tWin0, binc0, Pa, MROWS, HID, INDIM);
    gemm_hw<<<dim3(8, 128), 256, 0, stream>>>(Pa, tWt00, tWh00, btc0, bhc0, Pb, MROWS, HID, HID);
    gemm_hw<<<dim3(8, 128), 256, 0, stream>>>(Pb, tWt01, tWh01, btc0 + HID, bhc0 + HID, Pa, MROWS, HID, HID);
    cumsum_t<<<256, 256, 0, stream>>>(Pa);      // Pa = y0

    // ---- layer 1 ----
    gemm128<<<dim3(8, 128), 256, 0, stream>>>(Pa, tWin1, binc1, Pb, MROWS, HID, HID);
    gemm_hw<<<dim3(8, 128), 256, 0, stream>>>(Pb, tWt10, tWh10, btc1, bhc1, Pa, MROWS, HID, HID);
    // final depth stage: no 32 MB Hout — reduce over t directly into hfinal
    zero_hf<<<256, 256, 0, stream>>>(hfinal);
    gemm_hw_sum<<<dim3(8, 128), 256, 0, stream>>>(Pa, tWt11, tWh11, btc1 + HID, bhc1 + HID,
                                                  hfinal, MROWS, HID, HID);

    // ---- tail ----
    fc_final<<<64, 128, 0, stream>>>(hfinal, fc_W, fc_b, d_out);
}